// Round 1
// baseline (373.187 us; speedup 1.0000x reference)
//
#include <hip/hip_runtime.h>

// Problem constants (from reference):
//   x:            [64, 30, 30, 1024] fp32
//   pattern_idx:  [64, 30, 30]       int32, values in [0, 64)
//   spatial_pe:   [30, 30, 512]      fp32
//   pattern_pe:   [64, 512]          fp32
//   out = x + concat(spatial_pe[h,w,:], pattern_pe[idx[b,h,w],:])
#define D4      256   // 1024 floats / 4 per float4
#define HALF4   128   // 512 floats / 4
#define HWPIX   900   // 30*30

__global__ __launch_bounds__(256) void cpe_kernel(
    const float4* __restrict__ x,
    const int*    __restrict__ idx,
    const float4* __restrict__ spe,   // [900 * 128] float4
    const float4* __restrict__ ppe,   // [64  * 128] float4
    float4*       __restrict__ out,
    int n4)
{
    int g = blockIdx.x * blockDim.x + threadIdx.x;
    if (g >= n4) return;

    int c4  = g & (D4 - 1);   // float4 channel within pixel
    int pix = g >> 8;         // global pixel index (b*900 + h*30 + w)

    float4 xv = x[g];
    float4 pv;
    if (c4 < HALF4) {
        // spatial half: h*30+w == pix % 900 (H=W=MAX_GRID=30, full grid)
        int hw = pix % HWPIX;
        pv = spe[hw * HALF4 + c4];
    } else {
        // pattern half: gather by per-pixel index (L1/L2-resident table)
        unsigned p = (unsigned)idx[pix] & 63u;   // ref applies % 64
        pv = ppe[p * HALF4 + (c4 - HALF4)];
    }

    out[g] = make_float4(xv.x + pv.x, xv.y + pv.y, xv.z + pv.z, xv.w + pv.w);
}

extern "C" void kernel_launch(void* const* d_in, const int* in_sizes, int n_in,
                              void* d_out, int out_size, void* d_ws, size_t ws_size,
                              hipStream_t stream) {
    const float4* x   = (const float4*)d_in[0];
    const int*    idx = (const int*)   d_in[1];
    const float4* spe = (const float4*)d_in[2];
    const float4* ppe = (const float4*)d_in[3];
    float4*       out = (float4*)      d_out;

    int n4 = out_size / 4;               // 14,745,600 float4s
    int block = 256;
    int grid  = (n4 + block - 1) / block; // 57,600 blocks
    cpe_kernel<<<grid, block, 0, stream>>>(x, idx, spe, ppe, out, n4);
}